// Round 2
// baseline (833.959 us; speedup 1.0000x reference)
//
#include <hip/hip_runtime.h>

// Kalman filter: G=1024, T=200, S=16, M=4, fp32.
// One WAVE (64 lanes) per group; 4 independent waves per 256-thread block;
// grid = 256 (1 block/CU). No __syncthreads anywhere: waves are lockstep and
// DS ops complete in-order per wave, so cross-lane LDS handoffs need only
// "s_waitcnt lgkmcnt(0)" + a compiler reorder fence. vmcnt is never drained,
// so next-step global prefetch loads stay in flight under the whole step.
// All LDS IO is b128 (stride-20 rows -> <=2-way bank aliasing, free).
// Lane l: (i = l>>2, c = l&3) owns cov chunk cov[i][4c..4c+3] in registers.

constexpr int Gc = 1024;
constexpr int Tc = 200;

// wave-synchronous phase boundary: force LDS completion, forbid compiler
// motion of memory ops across it (rule #18: sched_barrier after asm waitcnt)
#define WSYNC() do {                                         \
    asm volatile("s_waitcnt lgkmcnt(0)" ::: "memory");       \
    __builtin_amdgcn_sched_barrier(0);                       \
} while (0)

struct __align__(16) GroupLds {
    float F[320];     // 16 rows x stride 20
    float Cov[320];
    float CovU[320];
    float Tmp[320];
    float H[80];      // 4 rows x stride 20
    float HP[80];
    float K[64];      // 16x4 row-major
    float S[16];
    float Cof[16];
    float R[16];
    float Mean[16];
    float MeanU[16];
    float Resid[4];
    float Y[4];
};

__global__ __launch_bounds__(256, 1)
void kalman_kernel(const float* __restrict__ y,        // [G,T,4]
                   const float* __restrict__ F,        // [G,T,16,16]
                   const float* __restrict__ H,        // [G,T,4,16]
                   const float* __restrict__ Q,        // [G,T,16,16]
                   const float* __restrict__ R,        // [G,T,4,4]
                   const float* __restrict__ initMean, // [G,16]
                   const float* __restrict__ initCov,  // [G,16,16]
                   float* __restrict__ out)
{
    __shared__ GroupLds lds[4];
    const int tid = threadIdx.x;
    const int w   = tid >> 6;          // wave in block = group in block
    const int l   = tid & 63;          // lane
    GroupLds& L = lds[w];
    const int g   = blockIdx.x * 4 + w;
    const int i   = l >> 2;            // 0..15 (row for cov chunks)
    const int c   = l & 3;             // 0..3  (col chunk)
    const int m4  = l >> 4;            // 0..3  (obs row in phase B)
    const int s16 = l & 15;            // 0..15 (state col in phase B)
    const size_t gT = (size_t)g * Tc;

    float* outMeans = out;
    float* outCovs  = out + (size_t)Gc * Tc * 16;
    float* outRp    = outCovs + (size_t)Gc * Tc * 256;
    float* outHp    = outRp + (size_t)Gc * Tc * 16;

    const float* pF = F + gT * 256 + 4 * l;
    const float* pQ = Q + gT * 256 + 4 * l;
    const float* pH = H + gT * 64 + 4 * s16;
    const float* pR = R + gT * 16 + 4 * c;
    const float* pY = y + gT * 4;
    float* pOutM = outMeans + gT * 16 + 4 * c;
    float* pOutC = outCovs + gT * 256 + 4 * l;
    float* pOutR = outRp + gT * 16 + 4 * c;
    float* pOutH = outHp + gT * 64 + 4 * s16;

    // ---- init state ----
    float4 covReg = *(const float4*)(initCov + (size_t)g * 256 + 4 * l);
    if (l < 16) L.Mean[l] = initMean[g * 16 + l];
    *(float4*)&L.Cov[i * 20 + 4 * c] = covReg;

    // ---- preload t=0 inputs into registers ----
    float4 fr = *(const float4*)pF;
    float4 qr = *(const float4*)pQ;
    float4 hr = {0, 0, 0, 0}, rr = {0, 0, 0, 0}, yr = {0, 0, 0, 0};
    if (l < 16) hr = *(const float4*)pH;
    if (l < 4)  rr = *(const float4*)pR;
    if (l == 0) yr = *(const float4*)pY;

    WSYNC();

    for (int t = 0; t < Tc; ++t) {
        // ---- A: emit outputs (pre-update state) + passthrough ----
        *(float4*)pOutC = covReg;
        if (l < 16) *(float4*)pOutH = hr;
        if (l < 4) {
            float4 mv = *(const float4*)&L.Mean[4 * l];
            *(float4*)pOutM = mv;
            *(float4*)pOutR = rr;
        }

        if (t == Tc - 1) break;   // uniform

        // ---- stage current step inputs into LDS (Q stays in registers) ----
        *(float4*)&L.F[i * 20 + 4 * c] = fr;
        if (l < 16) *(float4*)&L.H[(l >> 2) * 20 + 4 * (l & 3)] = hr;
        if (l < 4)  *(float4*)&L.R[4 * l] = rr;
        if (l == 0) *(float4*)&L.Y[0] = yr;
        float qc[4] = {qr.x, qr.y, qr.z, qr.w};

        // ---- prefetch next step (stays in flight under the whole step) ----
        pF += 256; pQ += 256; pH += 64; pR += 16; pY += 4;
        pOutM += 16; pOutC += 256; pOutR += 16; pOutH += 64;
        fr = *(const float4*)pF;
        qr = *(const float4*)pQ;
        if (l < 16) hr = *(const float4*)pH;
        if (l < 4)  rr = *(const float4*)pR;
        if (l == 0) yr = *(const float4*)pY;

        WSYNC();

        // ---- B: HP[m4][s16] = sum_n H[m4][n]*Cov[n][s16]; resid (l<4) ----
        {
            float h16[16];
            #pragma unroll
            for (int c2 = 0; c2 < 4; ++c2) {
                float4 v = *(const float4*)&L.H[m4 * 20 + 4 * c2];
                h16[4*c2] = v.x; h16[4*c2+1] = v.y; h16[4*c2+2] = v.z; h16[4*c2+3] = v.w;
            }
            float acc = 0.f;
            #pragma unroll
            for (int n = 0; n < 16; ++n) acc += h16[n] * L.Cov[n * 20 + s16];
            L.HP[m4 * 20 + s16] = acc;
        }
        if (l < 4) {
            const float* hrow = &L.H[l * 20];
            float4 h0 = *(const float4*)&hrow[0];
            float4 h1 = *(const float4*)&hrow[4];
            float4 h2 = *(const float4*)&hrow[8];
            float4 h3 = *(const float4*)&hrow[12];
            float4 n0 = *(const float4*)&L.Mean[0];
            float4 n1 = *(const float4*)&L.Mean[4];
            float4 n2 = *(const float4*)&L.Mean[8];
            float4 n3 = *(const float4*)&L.Mean[12];
            float acc = L.Y[l]
                - (h0.x*n0.x + h0.y*n0.y + h0.z*n0.z + h0.w*n0.w)
                - (h1.x*n1.x + h1.y*n1.y + h1.z*n1.z + h1.w*n1.w)
                - (h2.x*n2.x + h2.y*n2.y + h2.z*n2.z + h2.w*n2.w)
                - (h3.x*n3.x + h3.y*n3.y + h3.z*n3.z + h3.w*n3.w);
            L.Resid[l] = acc;
        }
        WSYNC();

        // ---- C: Ssig[m][k2] = R + sum_n HP[m][n]*H[k2][n]  (l<16) ----
        if (l < 16) {
            const int mm = l >> 2, k2 = l & 3;
            float hp16[16], hk16[16];
            #pragma unroll
            for (int c2 = 0; c2 < 4; ++c2) {
                float4 a4 = *(const float4*)&L.HP[mm * 20 + 4 * c2];
                hp16[4*c2] = a4.x; hp16[4*c2+1] = a4.y; hp16[4*c2+2] = a4.z; hp16[4*c2+3] = a4.w;
                float4 b4 = *(const float4*)&L.H[k2 * 20 + 4 * c2];
                hk16[4*c2] = b4.x; hk16[4*c2+1] = b4.y; hk16[4*c2+2] = b4.z; hk16[4*c2+3] = b4.w;
            }
            float acc = L.R[l];
            #pragma unroll
            for (int n = 0; n < 16; ++n) acc += hp16[n] * hk16[n];
            L.S[l] = acc;
        }
        WSYNC();

        // ---- D: cofactors of 4x4 Ssig (l<16) ----
        if (l < 16) {
            const int mm = l >> 2, kk = l & 3;
            const int r0 = (mm == 0) ? 1 : 0;
            const int r1 = (mm <= 1) ? 2 : 1;
            const int r2 = (mm <= 2) ? 3 : 2;
            const int c0 = (kk == 0) ? 1 : 0;
            const int c1 = (kk <= 1) ? 2 : 1;
            const int c2 = (kk <= 2) ? 3 : 2;
            const float sa = L.S[r0*4+c0], sb = L.S[r0*4+c1], sc = L.S[r0*4+c2];
            const float sd = L.S[r1*4+c0], se = L.S[r1*4+c1], sf = L.S[r1*4+c2];
            const float sp = L.S[r2*4+c0], sq = L.S[r2*4+c1], sr = L.S[r2*4+c2];
            const float det3 = sa*(se*sr - sf*sq) - sb*(sd*sr - sf*sp) + sc*(sd*sq - se*sp);
            L.Cof[l] = ((mm + kk) & 1) ? -det3 : det3;
        }
        WSYNC();

        // ---- E: K[s][m] = (1/det) sum_k Cof[k][m]*HP[k][s]  (all lanes) ----
        {
            const int s = l >> 2, m = l & 3;
            float4 s0  = *(const float4*)&L.S[0];
            float4 cf0 = *(const float4*)&L.Cof[0];
            const float det = s0.x*cf0.x + s0.y*cf0.y + s0.z*cf0.z + s0.w*cf0.w;
            const float num = L.Cof[m]      * L.HP[s]
                            + L.Cof[4 + m]  * L.HP[20 + s]
                            + L.Cof[8 + m]  * L.HP[40 + s]
                            + L.Cof[12 + m] * L.HP[60 + s];
            L.K[l] = num / det;   // l == 4*s + m
        }
        WSYNC();

        // ---- F: covU = cov - K*HP (chunked); meanU (l<16) ----
        {
            float4 kr = *(const float4*)&L.K[i * 4];
            float4 hp0 = *(const float4*)&L.HP[0*20 + 4*c];
            float4 hp1 = *(const float4*)&L.HP[1*20 + 4*c];
            float4 hp2 = *(const float4*)&L.HP[2*20 + 4*c];
            float4 hp3 = *(const float4*)&L.HP[3*20 + 4*c];
            float4 acc = covReg;
            acc.x -= kr.x*hp0.x + kr.y*hp1.x + kr.z*hp2.x + kr.w*hp3.x;
            acc.y -= kr.x*hp0.y + kr.y*hp1.y + kr.z*hp2.y + kr.w*hp3.y;
            acc.z -= kr.x*hp0.z + kr.y*hp1.z + kr.z*hp2.z + kr.w*hp3.z;
            acc.w -= kr.x*hp0.w + kr.y*hp1.w + kr.z*hp2.w + kr.w*hp3.w;
            *(float4*)&L.CovU[i * 20 + 4 * c] = acc;
        }
        if (l < 16) {
            float4 kr = *(const float4*)&L.K[l * 4];
            float4 rs = *(const float4*)&L.Resid[0];
            L.MeanU[l] = L.Mean[l] + kr.x*rs.x + kr.y*rs.y + kr.z*rs.z + kr.w*rs.w;
        }
        WSYNC();

        // ---- G: tmp = F*covU (chunked); meanP = F*meanU -> Mean (l<16) ----
        {
            float f16[16];
            #pragma unroll
            for (int c2 = 0; c2 < 4; ++c2) {
                float4 v = *(const float4*)&L.F[i * 20 + 4 * c2];
                f16[4*c2] = v.x; f16[4*c2+1] = v.y; f16[4*c2+2] = v.z; f16[4*c2+3] = v.w;
            }
            float ax = 0.f, ay = 0.f, az = 0.f, aw = 0.f;
            #pragma unroll
            for (int j = 0; j < 16; ++j) {
                float4 cu = *(const float4*)&L.CovU[j * 20 + 4 * c];
                ax += f16[j]*cu.x; ay += f16[j]*cu.y; az += f16[j]*cu.z; aw += f16[j]*cu.w;
            }
            float4 tv; tv.x = ax; tv.y = ay; tv.z = az; tv.w = aw;
            *(float4*)&L.Tmp[i * 20 + 4 * c] = tv;
        }
        if (l < 16) {
            float fs[16], mu[16];
            #pragma unroll
            for (int c2 = 0; c2 < 4; ++c2) {
                float4 v = *(const float4*)&L.F[l * 20 + 4 * c2];
                fs[4*c2] = v.x; fs[4*c2+1] = v.y; fs[4*c2+2] = v.z; fs[4*c2+3] = v.w;
                float4 u = *(const float4*)&L.MeanU[4 * c2];
                mu[4*c2] = u.x; mu[4*c2+1] = u.y; mu[4*c2+2] = u.z; mu[4*c2+3] = u.w;
            }
            float acc = 0.f;
            #pragma unroll
            for (int j = 0; j < 16; ++j) acc += fs[j] * mu[j];
            L.Mean[l] = acc;   // old Mean no longer needed
        }
        WSYNC();

        // ---- H: cov = tmp*F' + Q (chunked, Q from registers) ----
        {
            float t16[16];
            #pragma unroll
            for (int c2 = 0; c2 < 4; ++c2) {
                float4 v = *(const float4*)&L.Tmp[i * 20 + 4 * c2];
                t16[4*c2] = v.x; t16[4*c2+1] = v.y; t16[4*c2+2] = v.z; t16[4*c2+3] = v.w;
            }
            float accv[4];
            #pragma unroll
            for (int r = 0; r < 4; ++r) {
                const float* frow = &L.F[(4 * c + r) * 20];
                float4 f0 = *(const float4*)&frow[0];
                float4 f1 = *(const float4*)&frow[4];
                float4 f2 = *(const float4*)&frow[8];
                float4 f3 = *(const float4*)&frow[12];
                float a = qc[r];
                a += t16[0]*f0.x + t16[1]*f0.y + t16[2]*f0.z + t16[3]*f0.w;
                a += t16[4]*f1.x + t16[5]*f1.y + t16[6]*f1.z + t16[7]*f1.w;
                a += t16[8]*f2.x + t16[9]*f2.y + t16[10]*f2.z + t16[11]*f2.w;
                a += t16[12]*f3.x + t16[13]*f3.y + t16[14]*f3.z + t16[15]*f3.w;
                accv[r] = a;
            }
            covReg.x = accv[0]; covReg.y = accv[1]; covReg.z = accv[2]; covReg.w = accv[3];
            *(float4*)&L.Cov[i * 20 + 4 * c] = covReg;
        }
        WSYNC();
    }
}

extern "C" void kernel_launch(void* const* d_in, const int* in_sizes, int n_in,
                              void* d_out, int out_size, void* d_ws, size_t ws_size,
                              hipStream_t stream) {
    const float* y        = (const float*)d_in[0];
    const float* F        = (const float*)d_in[1];
    const float* H        = (const float*)d_in[2];
    const float* Q        = (const float*)d_in[3];
    const float* R        = (const float*)d_in[4];
    const float* initMean = (const float*)d_in[5];
    const float* initCov  = (const float*)d_in[6];
    float* out = (float*)d_out;

    kalman_kernel<<<Gc / 4, 256, 0, stream>>>(y, F, H, Q, R, initMean, initCov, out);
}